// Round 1
// baseline (5167.124 us; speedup 1.0000x reference)
//
#include <hip/hip_runtime.h>
#include <hip/hip_fp16.h>
#include <stdint.h>

typedef _Float16 f16;
typedef _Float16 f16x8 __attribute__((ext_vector_type(8)));
typedef _Float16 f16x4 __attribute__((ext_vector_type(4)));
typedef float f32x4 __attribute__((ext_vector_type(4)));

#define DEV __device__ __forceinline__

DEV void gload_lds16(const void* g, void* l) {
    __builtin_amdgcn_global_load_lds(
        (const __attribute__((address_space(1))) void*)g,
        (__attribute__((address_space(3))) void*)l, 16, 0, 0);
}

// ---------------------------------------------------------------------------
// Split-fp16 GEMM: C = (Ahi+Alo) @ (Bhi+Blo)^T   (drops lo*lo term, ~2^-22)
// A: [M,K] rows m0.., B: [N,K] rows n0.., lda=ldb=K. 128x128 tile, BK=32.
// EPI==0: write f32 C (ldc).  EPI==1: write (hi,lo) fp16 pair of (C + bias).
// ---------------------------------------------------------------------------
template <int EPI>
__global__ __launch_bounds__(256, 2) void gemm_split3(
    const f16* __restrict__ Ahi, const f16* __restrict__ Alo,
    const f16* __restrict__ Bhi, const f16* __restrict__ Blo,
    int K, int ldc,
    float* __restrict__ Cf, f16* __restrict__ Chi, f16* __restrict__ Clo,
    const float* __restrict__ bias)
{
    __shared__ alignas(16) f16 As_hi[128 * 32];
    __shared__ alignas(16) f16 As_lo[128 * 32];
    __shared__ alignas(16) f16 Bs_hi[128 * 32];
    __shared__ alignas(16) f16 Bs_lo[128 * 32];
    const int t = threadIdx.x;
    const int lane = t & 63;
    const int w = t >> 6;
    const size_t m0 = (size_t)blockIdx.y * 128;
    const size_t n0 = (size_t)blockIdx.x * 128;
    const int wrow = (w >> 1) * 64;
    const int wcol = (w & 1) * 64;

    f32x4 acc[4][4] = {};

    for (int k0 = 0; k0 < K; k0 += 32) {
        __syncthreads();
#pragma unroll
        for (int i = 0; i < 2; ++i) {
            const int c = i * 256 + t;
            const int row = c >> 2;
            const int col = (c & 3) << 3;
            const int loff = (i * 256 + w * 64) * 8;  // f16 elements
            const size_t ga = (m0 + row) * (size_t)K + k0 + col;
            const size_t gb = (n0 + row) * (size_t)K + k0 + col;
            gload_lds16(Ahi + ga, &As_hi[loff]);
            gload_lds16(Alo + ga, &As_lo[loff]);
            gload_lds16(Bhi + gb, &Bs_hi[loff]);
            gload_lds16(Blo + gb, &Bs_lo[loff]);
        }
        __syncthreads();
        const int fr = lane & 15;
        const int fk = (lane >> 4) << 3;
        f16x8 ah[4], al[4], bh[4], bl[4];
#pragma unroll
        for (int x = 0; x < 4; ++x) {
            ah[x] = *(const f16x8*)&As_hi[(wrow + x * 16 + fr) * 32 + fk];
            al[x] = *(const f16x8*)&As_lo[(wrow + x * 16 + fr) * 32 + fk];
            bh[x] = *(const f16x8*)&Bs_hi[(wcol + x * 16 + fr) * 32 + fk];
            bl[x] = *(const f16x8*)&Bs_lo[(wcol + x * 16 + fr) * 32 + fk];
        }
#pragma unroll
        for (int mi = 0; mi < 4; ++mi)
#pragma unroll
            for (int ni = 0; ni < 4; ++ni) {
                acc[mi][ni] = __builtin_amdgcn_mfma_f32_16x16x32_f16(ah[mi], bh[ni], acc[mi][ni], 0, 0, 0);
                acc[mi][ni] = __builtin_amdgcn_mfma_f32_16x16x32_f16(ah[mi], bl[ni], acc[mi][ni], 0, 0, 0);
                acc[mi][ni] = __builtin_amdgcn_mfma_f32_16x16x32_f16(al[mi], bh[ni], acc[mi][ni], 0, 0, 0);
            }
    }

    const int fr = lane & 15;
    const int fq = lane >> 4;
#pragma unroll
    for (int mi = 0; mi < 4; ++mi)
#pragma unroll
        for (int ni = 0; ni < 4; ++ni)
#pragma unroll
            for (int r = 0; r < 4; ++r) {
                const size_t row = m0 + wrow + mi * 16 + fq * 4 + r;
                const size_t col = n0 + wcol + ni * 16 + fr;
                float v = acc[mi][ni][r];
                if constexpr (EPI == 0) {
                    Cf[row * (size_t)ldc + col] = v;
                } else {
                    v += bias[col];
                    const f16 h = (f16)v;
                    Chi[row * (size_t)ldc + col] = h;
                    Clo[row * (size_t)ldc + col] = (f16)(v - (float)h);
                }
            }
}

// ---------------------------------------------------------------------------
// Single fp16 GEMM: C(fp16) = A @ B^T. A:[M,K] B:[N,K], lda=ldb=K.
// ---------------------------------------------------------------------------
__global__ __launch_bounds__(256, 2) void gemm_f16(
    const f16* __restrict__ A, const f16* __restrict__ B,
    int K, int ldc, f16* __restrict__ C)
{
    __shared__ alignas(16) f16 As[128 * 32];
    __shared__ alignas(16) f16 Bs[128 * 32];
    const int t = threadIdx.x;
    const int lane = t & 63;
    const int w = t >> 6;
    const size_t m0 = (size_t)blockIdx.y * 128;
    const size_t n0 = (size_t)blockIdx.x * 128;
    const int wrow = (w >> 1) * 64;
    const int wcol = (w & 1) * 64;

    f32x4 acc[4][4] = {};

    for (int k0 = 0; k0 < K; k0 += 32) {
        __syncthreads();
#pragma unroll
        for (int i = 0; i < 2; ++i) {
            const int c = i * 256 + t;
            const int row = c >> 2;
            const int col = (c & 3) << 3;
            const int loff = (i * 256 + w * 64) * 8;
            gload_lds16(A + (m0 + row) * (size_t)K + k0 + col, &As[loff]);
            gload_lds16(B + (n0 + row) * (size_t)K + k0 + col, &Bs[loff]);
        }
        __syncthreads();
        const int fr = lane & 15;
        const int fk = (lane >> 4) << 3;
        f16x8 a[4], b[4];
#pragma unroll
        for (int x = 0; x < 4; ++x) {
            a[x] = *(const f16x8*)&As[(wrow + x * 16 + fr) * 32 + fk];
            b[x] = *(const f16x8*)&Bs[(wcol + x * 16 + fr) * 32 + fk];
        }
#pragma unroll
        for (int mi = 0; mi < 4; ++mi)
#pragma unroll
            for (int ni = 0; ni < 4; ++ni)
                acc[mi][ni] = __builtin_amdgcn_mfma_f32_16x16x32_f16(a[mi], b[ni], acc[mi][ni], 0, 0, 0);
    }

    const int fr = lane & 15;
    const int fq = lane >> 4;
#pragma unroll
    for (int mi = 0; mi < 4; ++mi)
#pragma unroll
        for (int ni = 0; ni < 4; ++ni)
#pragma unroll
            for (int r = 0; r < 4; ++r) {
                const size_t row = m0 + wrow + mi * 16 + fq * 4 + r;
                const size_t col = n0 + wcol + ni * 16 + fr;
                C[row * (size_t)ldc + col] = (f16)acc[mi][ni][r];
            }
}

// ---------------------------------------------------------------------------
// Final GEMM: Out = tanh(cat @ B^T + bias), cat from 3 segments of K=1024
// each (A0=att_hi, A1=ctx_ss, A2=ctx_es), B = Wlin fp16 [1024, 3072].
// ---------------------------------------------------------------------------
__global__ __launch_bounds__(256, 2) void gemm_final(
    const f16* __restrict__ A0, const f16* __restrict__ A1,
    const f16* __restrict__ A2, const f16* __restrict__ B,
    const float* __restrict__ bias, float* __restrict__ Out)
{
    __shared__ alignas(16) f16 As[128 * 32];
    __shared__ alignas(16) f16 Bs[128 * 32];
    const int t = threadIdx.x;
    const int lane = t & 63;
    const int w = t >> 6;
    const size_t m0 = (size_t)blockIdx.y * 128;
    const size_t n0 = (size_t)blockIdx.x * 128;
    const int wrow = (w >> 1) * 64;
    const int wcol = (w & 1) * 64;
    const int K = 3072;

    f32x4 acc[4][4] = {};

    for (int k0 = 0; k0 < K; k0 += 32) {
        const f16* Aseg = (k0 < 1024) ? A0 : (k0 < 2048) ? A1 : A2;
        const int kl = k0 & 1023;
        __syncthreads();
#pragma unroll
        for (int i = 0; i < 2; ++i) {
            const int c = i * 256 + t;
            const int row = c >> 2;
            const int col = (c & 3) << 3;
            const int loff = (i * 256 + w * 64) * 8;
            gload_lds16(Aseg + (m0 + row) * (size_t)1024 + kl + col, &As[loff]);
            gload_lds16(B + (n0 + row) * (size_t)K + k0 + col, &Bs[loff]);
        }
        __syncthreads();
        const int fr = lane & 15;
        const int fk = (lane >> 4) << 3;
        f16x8 a[4], b[4];
#pragma unroll
        for (int x = 0; x < 4; ++x) {
            a[x] = *(const f16x8*)&As[(wrow + x * 16 + fr) * 32 + fk];
            b[x] = *(const f16x8*)&Bs[(wcol + x * 16 + fr) * 32 + fk];
        }
#pragma unroll
        for (int mi = 0; mi < 4; ++mi)
#pragma unroll
            for (int ni = 0; ni < 4; ++ni)
                acc[mi][ni] = __builtin_amdgcn_mfma_f32_16x16x32_f16(a[mi], b[ni], acc[mi][ni], 0, 0, 0);
    }

    const int fr = lane & 15;
    const int fq = lane >> 4;
#pragma unroll
    for (int mi = 0; mi < 4; ++mi)
#pragma unroll
        for (int ni = 0; ni < 4; ++ni)
#pragma unroll
            for (int r = 0; r < 4; ++r) {
                const size_t row = m0 + wrow + mi * 16 + fq * 4 + r;
                const size_t col = n0 + wcol + ni * 16 + fr;
                Out[row * 1024 + col] = tanhf(acc[mi][ni][r] + bias[col]);
            }
}

// ---------------------------------------------------------------------------
// Row softmax: one block per row of length C*1024 f32, write fp16 weights.
// ---------------------------------------------------------------------------
template <int C>
__global__ __launch_bounds__(256) void softmax_row(
    const float* __restrict__ S, f16* __restrict__ W)
{
    const size_t base = (size_t)blockIdx.x * (C * 1024);
    const float* s = S + base;
    f16* w = W + base;
    const int t = threadIdx.x;
    f32x4 v[C];
    float mx = -3.0e38f;
#pragma unroll
    for (int i = 0; i < C; ++i) {
        v[i] = *(const f32x4*)&s[(t + i * 256) * 4];
        mx = fmaxf(mx, fmaxf(fmaxf(v[i][0], v[i][1]), fmaxf(v[i][2], v[i][3])));
    }
#pragma unroll
    for (int off = 32; off; off >>= 1) mx = fmaxf(mx, __shfl_xor(mx, off));
    __shared__ float red[8];
    if ((t & 63) == 0) red[t >> 6] = mx;
    __syncthreads();
    mx = fmaxf(fmaxf(red[0], red[1]), fmaxf(red[2], red[3]));
    float sm = 0.f;
#pragma unroll
    for (int i = 0; i < C; ++i) {
        v[i][0] = __expf(v[i][0] - mx);
        v[i][1] = __expf(v[i][1] - mx);
        v[i][2] = __expf(v[i][2] - mx);
        v[i][3] = __expf(v[i][3] - mx);
        sm += (v[i][0] + v[i][1]) + (v[i][2] + v[i][3]);
    }
#pragma unroll
    for (int off = 32; off; off >>= 1) sm += __shfl_xor(sm, off);
    if ((t & 63) == 0) red[4 + (t >> 6)] = sm;
    __syncthreads();
    sm = (red[4] + red[5]) + (red[6] + red[7]);
    const float inv = 1.f / sm;
#pragma unroll
    for (int i = 0; i < C; ++i) {
        f16x4 o;
        o[0] = (f16)(v[i][0] * inv);
        o[1] = (f16)(v[i][1] * inv);
        o[2] = (f16)(v[i][2] * inv);
        o[3] = (f16)(v[i][3] * inv);
        *(f16x4*)&w[(t + i * 256) * 4] = o;
    }
}

// ---------------------------------------------------------------------------
// Transpose X[N,H] f32 -> Xt[H,N] fp16 (64x64 tiles via LDS)
// ---------------------------------------------------------------------------
__global__ __launch_bounds__(256) void transpose_f32_to_f16(
    const float* __restrict__ X, f16* __restrict__ Xt, int N, int H)
{
    __shared__ float tile[64][65];
    const int n0 = blockIdx.x * 64;
    const int h0 = blockIdx.y * 64;
    const int tx = threadIdx.x & 15;
    const int ty = threadIdx.x >> 4;
#pragma unroll
    for (int i = 0; i < 4; ++i) {
        const int r = ty + i * 16;
        const f32x4 vv = *(const f32x4*)&X[(size_t)(n0 + r) * H + h0 + tx * 4];
        tile[r][tx * 4 + 0] = vv[0];
        tile[r][tx * 4 + 1] = vv[1];
        tile[r][tx * 4 + 2] = vv[2];
        tile[r][tx * 4 + 3] = vv[3];
    }
    __syncthreads();
#pragma unroll
    for (int i = 0; i < 4; ++i) {
        const int hh = ty + i * 16;
        f16x4 o;
        o[0] = (f16)tile[tx * 4 + 0][hh];
        o[1] = (f16)tile[tx * 4 + 1][hh];
        o[2] = (f16)tile[tx * 4 + 2][hh];
        o[3] = (f16)tile[tx * 4 + 3][hh];
        *(f16x4*)&Xt[(size_t)(h0 + hh) * N + n0 + tx * 4] = o;
    }
}

// ---------------------------------------------------------------------------
// Elementwise converters
// ---------------------------------------------------------------------------
__global__ __launch_bounds__(256) void split_f32_f16(
    const float* __restrict__ X, f16* __restrict__ hi, f16* __restrict__ lo)
{
    const size_t i = ((size_t)blockIdx.x * 256 + threadIdx.x) * 4;
    const f32x4 v = *(const f32x4*)&X[i];
    f16x4 h, l;
#pragma unroll
    for (int j = 0; j < 4; ++j) {
        h[j] = (f16)v[j];
        l[j] = (f16)(v[j] - (float)h[j]);
    }
    *(f16x4*)&hi[i] = h;
    *(f16x4*)&lo[i] = l;
}

__global__ __launch_bounds__(256) void conv_f32_f16(
    const float* __restrict__ X, f16* __restrict__ Y)
{
    const size_t i = ((size_t)blockIdx.x * 256 + threadIdx.x) * 4;
    const f32x4 v = *(const f32x4*)&X[i];
    f16x4 h;
#pragma unroll
    for (int j = 0; j < 4; ++j) h[j] = (f16)v[j];
    *(f16x4*)&Y[i] = h;
}

// ---------------------------------------------------------------------------
extern "C" void kernel_launch(void* const* d_in, const int* in_sizes, int n_in,
                              void* d_out, int out_size, void* d_ws, size_t ws_size,
                              hipStream_t stream)
{
    (void)in_sizes; (void)n_in; (void)out_size;
    constexpr int Ns = 8192, Ne = 4096, M = 8192, H = 1024, K3 = 3072, AO = 1024;

    const float* Xss  = (const float*)d_in[0];
    const float* Xes  = (const float*)d_in[1];
    const float* Att  = (const float*)d_in[2];
    const float* Wss  = (const float*)d_in[3];
    const float* bss  = (const float*)d_in[4];
    const float* Wes  = (const float*)d_in[5];
    const float* bes  = (const float*)d_in[6];
    const float* Wlin = (const float*)d_in[7];
    const float* blin = (const float*)d_in[8];
    float* Out = (float*)d_out;

    // ---- workspace layout ----
    char* p = (char*)d_ws;
    auto carve = [&](size_t bytes) {
        char* r = p;
        p += (bytes + 255) & ~(size_t)255;
        return r;
    };
    f16* Att_hi = (f16*)carve((size_t)M * H * 2);
    f16* Att_lo = (f16*)carve((size_t)M * H * 2);
    f16* Xss_hi = (f16*)carve((size_t)Ns * H * 2);
    f16* Xss_lo = (f16*)carve((size_t)Ns * H * 2);
    f16* Xes_hi = (f16*)carve((size_t)Ne * H * 2);
    f16* Xes_lo = (f16*)carve((size_t)Ne * H * 2);
    f16* Wss_hi = (f16*)carve((size_t)H * H * 2);
    f16* Wss_lo = (f16*)carve((size_t)H * H * 2);
    f16* Wes_hi = (f16*)carve((size_t)H * H * 2);
    f16* Wes_lo = (f16*)carve((size_t)H * H * 2);
    f16* Pss_hi = (f16*)carve((size_t)Ns * H * 2);
    f16* Pss_lo = (f16*)carve((size_t)Ns * H * 2);
    f16* Pes_hi = (f16*)carve((size_t)Ne * H * 2);
    f16* Pes_lo = (f16*)carve((size_t)Ne * H * 2);
    f16* Vtss   = (f16*)carve((size_t)H * Ns * 2);
    f16* Vtes   = (f16*)carve((size_t)H * Ne * 2);
    f16* Wl16   = (f16*)carve((size_t)AO * K3 * 2);
    f16* Ctxss  = (f16*)carve((size_t)M * H * 2);
    f16* Ctxes  = (f16*)carve((size_t)M * H * 2);

    const size_t static_bytes = (size_t)(p - (char*)d_ws);
    const size_t per_mc = (size_t)Ns * 4 + (size_t)Ne * 4 + (size_t)Ns * 2 + (size_t)Ne * 2;  // 73728 B/row
    int Mc = 2048;
    while (Mc > 128 && static_bytes + (size_t)Mc * per_mc + 4096 > ws_size) Mc >>= 1;
    if (static_bytes + (size_t)Mc * per_mc + 4096 > ws_size) return;  // ws too small: fail loudly

    float* Sss = (float*)carve((size_t)Mc * Ns * 4);
    float* Ses = (float*)carve((size_t)Mc * Ne * 4);
    f16* Wtss  = (f16*)carve((size_t)Mc * Ns * 2);
    f16* Wtes  = (f16*)carve((size_t)Mc * Ne * 2);

    // ---- stage 0: conversions ----
    split_f32_f16<<<(M * H) / 1024, 256, 0, stream>>>(Att, Att_hi, Att_lo);
    split_f32_f16<<<(Ns * H) / 1024, 256, 0, stream>>>(Xss, Xss_hi, Xss_lo);
    split_f32_f16<<<(Ne * H) / 1024, 256, 0, stream>>>(Xes, Xes_hi, Xes_lo);
    split_f32_f16<<<(H * H) / 1024, 256, 0, stream>>>(Wss, Wss_hi, Wss_lo);
    split_f32_f16<<<(H * H) / 1024, 256, 0, stream>>>(Wes, Wes_hi, Wes_lo);
    conv_f32_f16<<<(AO * K3) / 1024, 256, 0, stream>>>(Wlin, Wl16);
    transpose_f32_to_f16<<<dim3(Ns / 64, H / 64), 256, 0, stream>>>(Xss, Vtss, Ns, H);
    transpose_f32_to_f16<<<dim3(Ne / 64, H / 64), 256, 0, stream>>>(Xes, Vtes, Ne, H);

    // ---- stage 1: projections P = X @ W^T + b (split-fp16 precision) ----
    gemm_split3<1><<<dim3(H / 128, Ns / 128), 256, 0, stream>>>(
        Xss_hi, Xss_lo, Wss_hi, Wss_lo, H, H, nullptr, Pss_hi, Pss_lo, bss);
    gemm_split3<1><<<dim3(H / 128, Ne / 128), 256, 0, stream>>>(
        Xes_hi, Xes_lo, Wes_hi, Wes_lo, H, H, nullptr, Pes_hi, Pes_lo, bes);

    // ---- stage 2: per-M-chunk scores -> softmax -> context ----
    for (int m0 = 0; m0 < M; m0 += Mc) {
        gemm_split3<0><<<dim3(Ns / 128, Mc / 128), 256, 0, stream>>>(
            Att_hi + (size_t)m0 * H, Att_lo + (size_t)m0 * H, Pss_hi, Pss_lo,
            H, Ns, Sss, nullptr, nullptr, nullptr);
        gemm_split3<0><<<dim3(Ne / 128, Mc / 128), 256, 0, stream>>>(
            Att_hi + (size_t)m0 * H, Att_lo + (size_t)m0 * H, Pes_hi, Pes_lo,
            H, Ne, Ses, nullptr, nullptr, nullptr);
        softmax_row<8><<<Mc, 256, 0, stream>>>(Sss, Wtss);
        softmax_row<4><<<Mc, 256, 0, stream>>>(Ses, Wtes);
        gemm_f16<<<dim3(H / 128, Mc / 128), 256, 0, stream>>>(Wtss, Vtss, Ns, H, Ctxss + (size_t)m0 * H);
        gemm_f16<<<dim3(H / 128, Mc / 128), 256, 0, stream>>>(Wtes, Vtes, Ne, H, Ctxes + (size_t)m0 * H);
    }

    // ---- stage 3: out = tanh([att, ctx_ss, ctx_es] @ Wlin^T + b) ----
    gemm_final<<<dim3(AO / 128, M / 128), 256, 0, stream>>>(
        Att_hi, Ctxss, Ctxes, Wl16, blin, Out);
}